// Round 12
// baseline (901.611 us; speedup 1.0000x reference)
//
#include <hip/hip_runtime.h>
#include <math.h>

// Problem constants: B=1, C=256, H=96, W=96, N=8
#define CH   256
#define HH   96
#define WW   96
#define NN   8
#define HWSZ 9216
#define PLANE (HWSZ*CH)          // elements per neighbor in NHWC

typedef unsigned short u16;
typedef unsigned int   u32;
typedef short bf16x8 __attribute__((ext_vector_type(8)));
typedef float f32x4  __attribute__((ext_vector_type(4)));
typedef float f32x2  __attribute__((ext_vector_type(2)));

__device__ inline u16 f2bf(float f) {
    union { float f; u32 u; } v; v.f = f;
    u32 r = v.u + 0x7FFF + ((v.u >> 16) & 1);   // RNE
    return (u16)(r >> 16);
}
__device__ inline float bflo(u32 u) {
    union { u32 u; float f; } v; v.u = u << 16; return v.f;
}
__device__ inline float bfhi(u32 u) {
    union { u32 u; float f; } v; v.u = u & 0xffff0000u; return v.f;
}
__device__ inline u32 pk2bf(float lo, float hi) {   // RNE pack pair
    union { float f; u32 u; } a, b; a.f = lo; b.f = hi;
    u32 ra = a.u + 0x7FFF + ((a.u >> 16) & 1);
    u32 rb = b.u + 0x7FFF + ((b.u >> 16) & 1);
    return (ra >> 16) | (rb & 0xffff0000u);
}

// ---------------------------------------------------------------------------
__global__ void k_emb_sum(const float* __restrict__ cd,
                          const float* __restrict__ enc_w,
                          const float* __restrict__ enc_b,
                          float* __restrict__ emb)
{
    int c = threadIdx.x;
    float s = 0.f;
    for (int n = 0; n < NN; ++n) {
        float d = enc_b[c];
        #pragma unroll
        for (int j = 0; j < 4; ++j) d += cd[n*4 + j] * enc_w[c*4 + j];
        s += d;
    }
    emb[c] = s;
}

// ---------------------------------------------------------------------------
// NCHW f32 -> NHWC bf16 via LDS transpose; both sides coalesced.
__global__ __launch_bounds__(256) void k_to_nhwc(const float* __restrict__ in,
                                                 u16* __restrict__ out)
{
    int n = blockIdx.y;
    int p0 = blockIdx.x * 64;
    int tid = threadIdx.x;
    __shared__ u16 T[64][262];

    int px4 = (tid & 15) * 4, cb = tid >> 4;
    for (int it = 0; it < 16; ++it) {
        int c = cb + it*16;
        float4 v = *reinterpret_cast<const float4*>(
            in + ((size_t)n*CH + c)*HWSZ + p0 + px4);
        T[px4+0][c] = f2bf(v.x);
        T[px4+1][c] = f2bf(v.y);
        T[px4+2][c] = f2bf(v.z);
        T[px4+3][c] = f2bf(v.w);
    }
    __syncthreads();
    int pxb = tid >> 5, ck = tid & 31;
    for (int it = 0; it < 8; ++it) {
        int p = pxb + it*8;
        *reinterpret_cast<int4*>(out + (size_t)n*PLANE + (size_t)(p0+p)*CH + ck*8) =
            *reinterpret_cast<const int4*>(&T[p][ck*8]);
    }
}

// ---------------------------------------------------------------------------
// pack conv weights w[O][CIN][3][3] (fp32 OIHW) -> bf16 A-fragment layout.
// order 0: kc = tap*(CIN/32) + (c>>5)   (tap-major K)
// order 1: kc = (c>>5)*9 + tap          (chunk-major K)
__global__ void k_pack_w(const float* __restrict__ w, u16* __restrict__ wp,
                         int O, int O_pad, int CIN, int order)
{
    int idx = blockIdx.x * 256 + threadIdx.x;
    int total = O_pad * CIN * 9;
    if (idx >= total) return;
    int o = idx / (CIN * 9);
    int K = idx % (CIN * 9);
    int tap = K / CIN, c = K % CIN;
    float v = (o < O) ? w[((size_t)o * CIN + c) * 9 + tap] : 0.f;
    int NKC = (CIN * 9) >> 5;
    int kc = order ? ((c >> 5)*9 + tap) : (tap*(CIN >> 5) + (c >> 5));
    int kl = c & 31;
    int lane = (kl >> 3) * 16 + (o & 15);
    size_t dstp = (((size_t)(o >> 4) * NKC + kc) * 64 + lane) * 8 + (kl & 7);
    wp[dstp] = f2bf(v);
}

// ---------------------------------------------------------------------------
// shift-conv 3x3 pad1 on concat(in0_n, in1_n) (512 in-ch, NHWC bf16) via MFMA.
// tile 8 rows x 32 cols (256 px), grid (8, 36) [XCD-pinned n], block 512.
template<int MTW, int EPI>
__global__ __launch_bounds__(512) void k_conv_nhwc(
    const u16* __restrict__ in0, long s0,
    const u16* __restrict__ in1, long s1,
    const u16* __restrict__ Wp, const float* __restrict__ b1,
    const float* __restrict__ g2w, const float* __restrict__ g2b,
    float* __restrict__ out)
{
    constexpr int NKC = 144, NCC = 16;
    int n = blockIdx.x, t = blockIdx.y;
    int tx0 = (t % 3) * 32, ty0 = (t / 3) * 8;
    int tid = threadIdx.x, lane = tid & 63, w = tid >> 6;
    int mh = w >> 2, pg = w & 3;
    int colq = lane >> 4;

    __shared__ __align__(16) u16 SB[340*40];
    __shared__ float gpart[8][64];

    f32x4 acc[MTW][4];
    #pragma unroll
    for (int mt = 0; mt < MTW; ++mt)
        #pragma unroll
        for (int nf = 0; nf < 4; ++nf)
            acc[mt][nf] = (f32x4){0.f,0.f,0.f,0.f};

    int bidx[4];
    #pragma unroll
    for (int nf = 0; nf < 4; ++nf) {
        int px = pg*64 + nf*16 + (lane & 15);
        int row = px >> 5, col = px & 31;
        bidx[nf] = ((row+1)*34 + (col+1))*40 + colq*8;
    }

    for (int cc = 0; cc < NCC; ++cc) {
        const u16* base = (cc < 8) ? in0 + (size_t)n*s0 + cc*32
                                   : in1 + (size_t)n*s1 + (cc-8)*32;
        for (int i = tid; i < 1360; i += 512) {
            int ph = i >> 2, q = i & 3;
            int r = ph / 34, col = ph - r*34;
            int y = ty0 - 1 + r, x = tx0 - 1 + col;
            bool v = ((unsigned)y < (unsigned)HH) && ((unsigned)x < (unsigned)WW);
            int off = v ? (y*WW + x)*CH : 0;
            int4 val = *reinterpret_cast<const int4*>(base + off + q*8);
            if (!v) val = make_int4(0,0,0,0);
            *reinterpret_cast<int4*>(&SB[ph*40 + q*8]) = val;
        }
        __syncthreads();
        #pragma unroll
        for (int tap = 0; tap < 9; ++tap) {
            int kc = tap*NCC + cc;
            bf16x8 a[MTW];
            #pragma unroll
            for (int mt = 0; mt < MTW; ++mt)
                a[mt] = *reinterpret_cast<const bf16x8*>(
                    Wp + (((size_t)(mh*MTW+mt)*NKC + kc)*64 + lane)*8);
            const int dy = tap/3 - 1, dx = tap%3 - 1;
            #pragma unroll
            for (int nf = 0; nf < 4; ++nf) {
                bf16x8 b = *reinterpret_cast<const bf16x8*>(
                    &SB[bidx[nf] + (dy*34 + dx)*40]);
                #pragma unroll
                for (int mt = 0; mt < MTW; ++mt)
                    acc[mt][nf] = __builtin_amdgcn_mfma_f32_16x16x32_bf16(
                                      a[mt], b, acc[mt][nf], 0, 0, 0);
            }
        }
        __syncthreads();
    }

    if (EPI == 0) {
        #pragma unroll
        for (int nf = 0; nf < 4; ++nf) {
            int px = pg*64 + nf*16 + (lane & 15);
            int gp = (ty0 + (px>>5))*WW + tx0 + (px & 31);
            #pragma unroll
            for (int mt = 0; mt < MTW; ++mt) {
                int o_base = (mh*MTW+mt)*16 + colq*4;
                #pragma unroll
                for (int r = 0; r < 4; ++r) {
                    int o = o_base + r;
                    if (o < 18)
                        out[((size_t)n*18 + o)*HWSZ + gp] = acc[mt][nf][r] + b1[o];
                }
            }
        }
    } else {
        float part[4];
        #pragma unroll
        for (int nf = 0; nf < 4; ++nf) {
            float s = 0.f;
            #pragma unroll
            for (int mt = 0; mt < MTW; ++mt) {
                int o_base = (mh*MTW+mt)*16 + colq*4;
                #pragma unroll
                for (int r = 0; r < 4; ++r) {
                    int o = o_base + r;
                    float vv = fmaxf(acc[mt][nf][r] + b1[o], 0.f);
                    s += vv * g2w[o];
                }
            }
            part[nf] = s;
        }
        #pragma unroll
        for (int nf = 0; nf < 4; ++nf) {
            part[nf] += __shfl_xor(part[nf], 16, 64);
            part[nf] += __shfl_xor(part[nf], 32, 64);
        }
        if (lane < 16) {
            #pragma unroll
            for (int nf = 0; nf < 4; ++nf)
                gpart[w][nf*16 + lane] = part[nf];
        }
        __syncthreads();
        if (tid < 256) {
            int pxl = tid & 63, pgg = tid >> 6;
            float s = gpart[pgg][pxl] + gpart[4 + pgg][pxl] + g2b[0];
            float g = 1.f / (1.f + expf(-s));
            int px = pgg*64 + pxl;
            int gp = (ty0 + (px>>5))*WW + tx0 + (px & 31);
            out[(size_t)n*HWSZ + gp] = g;
        }
    }
}

// ---------------------------------------------------------------------------
// deformable 3x3 conv via bf16 MFMA, NHWC in/out. Barrier-free K-loop:
// per 32-ch chunk, stage an 8x40 halo window into LDS once (2 barriers/cc);
// each lane then builds its OWN MFMA B-fragments by bilerping directly from
// the window (4x ds_read_b128 + pk-FMA per fragment) -- no SB, no ds_write,
// no per-kc barrier.  Offsets outside the window (never, for this data's
// sigma~0.14 offsets; window covers |off|<2) -> block-uniform slow path.
// K-order chunk-major (kc = cc*9 + tap), pack order=1.
// tile 2 rows x 32 cols (64 px), grid (8, 144) [XCD-pinned n], block 256.
__global__ __launch_bounds__(256) void k_deform_nhwc(
    const u16* __restrict__ nbrh, const float* __restrict__ offs,
    const u16* __restrict__ Wp, const float* __restrict__ ab,
    u16* __restrict__ alig)
{
    constexpr int NKC = 72;
    int n = blockIdx.x, t = blockIdx.y;
    int tx0 = (t % 3) * 32, ty0 = (t / 3) * 2;
    int tid = threadIdx.x, lane = tid & 63, w = tid >> 6;
    int colq = lane >> 4, l15 = lane & 15;

    __shared__ __align__(16) u16 LW[14080];     // [8 r][40 c][44] = 28160 B
    __shared__ __align__(16) float4 wtab[576];  // 9216 B
    __shared__ int bitab[576];                  // 2304 B
    __shared__ int allok;

    const u16* src = nbrh + (size_t)n * PLANE;
    int4* cofsS = (int4*)LW;                    // slow-path corner offsets
    u16*  SBs   = LW + 4608;                    // slow-path staging buffer

    if (tid == 0) allok = 1;
    __syncthreads();

    // coords phase
    int myok = 1;
    for (int i = tid; i < 576; i += 256) {
        int tt = i >> 6, p = i & 63;
        int y = ty0 + (p>>5), x = tx0 + (p & 31);
        int pp = y*WW + x;
        float oy = offs[((size_t)n*18 + 2*tt    )*HWSZ + pp];
        float ox = offs[((size_t)n*18 + 2*tt + 1)*HWSZ + pp];
        float py  = (float)y + (float)(tt/3 - 1) + oy;
        float pxx = (float)x + (float)(tt%3 - 1) + ox;
        py  = fminf(fmaxf(py,  -4.f), 100.f);
        pxx = fminf(fmaxf(pxx, -4.f), 100.f);
        float y0f = floorf(py), x0f = floorf(pxx);
        int y0 = (int)y0f, x0 = (int)x0f;
        float wy = py - y0f, wx = pxx - x0f;
        bool b00 = (y0 >= 0)  & (y0 < HH)   & (x0 >= 0)  & (x0 < WW);
        bool b01 = (y0 >= 0)  & (y0 < HH)   & (x0 >= -1) & (x0 < WW-1);
        bool b10 = (y0 >= -1) & (y0 < HH-1) & (x0 >= 0)  & (x0 < WW);
        bool b11 = (y0 >= -1) & (y0 < HH-1) & (x0 >= -1) & (x0 < WW-1);
        float4 w4;
        w4.x = b00 ? (1.f-wy)*(1.f-wx) : 0.f;
        w4.y = b01 ? (1.f-wy)*wx       : 0.f;
        w4.z = b10 ? wy*(1.f-wx)       : 0.f;
        w4.w = b11 ? wy*wx             : 0.f;
        wtab[i] = w4;
        // window-local base (clamped so fast path can never OOB)
        bool inw = (y0 >= ty0-3) & (y0 <= ty0+3) & (x0 >= tx0-3) & (x0 <= tx0+35);
        int rr  = min(max(y0-(ty0-3), 0), 6);
        int ccl = min(max(x0-(tx0-3), 0), 38);
        bitab[i] = (rr*40 + ccl)*44;
        if (!inw) myok = 0;
        // slow-path global corner offsets
        int a00 = (y0*WW + x0)*CH;
        int4 o4;
        o4.x = b00 ? a00             : 0;
        o4.y = b01 ? a00 + CH        : 0;
        o4.z = b10 ? a00 + WW*CH     : 0;
        o4.w = b11 ? a00 + WW*CH+CH  : 0;
        cofsS[i] = o4;
    }
    if (!myok) atomicAnd(&allok, 0);
    __syncthreads();
    bool fast = (allok != 0);

    f32x4 acc[4][4];
    #pragma unroll
    for (int mt = 0; mt < 4; ++mt)
        #pragma unroll
        for (int nf = 0; nf < 4; ++nf)
            acc[mt][nf] = (f32x4){0.f,0.f,0.f,0.f};

    bf16x8 apf[4];
    auto loadA = [&](int kc) {
        #pragma unroll
        for (int mt = 0; mt < 4; ++mt)
            apf[mt] = *reinterpret_cast<const bf16x8*>(
                Wp + (((size_t)(w*4+mt)*NKC + kc)*64 + lane)*8);
    };
    auto bilerp = [&](float4 wt, int4 q0, int4 q1, int4 q2, int4 q3) -> bf16x8 {
        f32x2 W00 = {wt.x, wt.x}, W01 = {wt.y, wt.y};
        f32x2 W10 = {wt.z, wt.z}, W11 = {wt.w, wt.w};
        int4 res;
        #pragma unroll
        for (int j = 0; j < 4; ++j) {
            u32 u00 = ((const u32*)&q0)[j], u01 = ((const u32*)&q1)[j];
            u32 u10 = ((const u32*)&q2)[j], u11 = ((const u32*)&q3)[j];
            f32x2 c00 = {bflo(u00), bfhi(u00)};
            f32x2 c01 = {bflo(u01), bfhi(u01)};
            f32x2 c10 = {bflo(u10), bfhi(u10)};
            f32x2 c11 = {bflo(u11), bfhi(u11)};
            f32x2 v = c00*W00;
            v += c01*W01;
            v += c10*W10;
            v += c11*W11;
            ((u32*)&res)[j] = pk2bf(v.x, v.y);
        }
        union { int4 i4; bf16x8 b8; } cv; cv.i4 = res; return cv.b8;
    };

    if (fast) {
        // -------- fast path: LDS window, barrier-free tap loop --------
        loadA(0);
        for (int cc2 = 0; cc2 < 8; ++cc2) {
            __syncthreads();                 // all reads of LW(cc2-1) done
            for (int u = tid; u < 1280; u += 256) {
                int wp2 = u >> 2, q = u & 3;
                int row = wp2 / 40, col = wp2 - row*40;
                int y = ty0 - 3 + row, x = tx0 - 3 + col;
                bool v = ((unsigned)y < (unsigned)HH) && ((unsigned)x < (unsigned)WW);
                int4 val = v ? *reinterpret_cast<const int4*>(
                                   src + (y*WW + x)*CH + cc2*32 + q*8)
                             : make_int4(0,0,0,0);
                *reinterpret_cast<int4*>(&LW[(row*40+col)*44 + q*8]) = val;
            }
            __syncthreads();                 // LW(cc2) ready
            #pragma unroll
            for (int tap = 0; tap < 9; ++tap) {
                int kc = cc2*9 + tap;
                bf16x8 a4[4];
                #pragma unroll
                for (int mt = 0; mt < 4; ++mt) a4[mt] = apf[mt];
                if (kc + 1 < NKC) loadA(kc + 1);
                #pragma unroll
                for (int nf = 0; nf < 4; ++nf) {
                    int r = tap*64 + nf*16 + l15;
                    int base = bitab[r] + colq*8;
                    float4 wt = wtab[r];
                    int4 q0 = *reinterpret_cast<const int4*>(&LW[base]);
                    int4 q1 = *reinterpret_cast<const int4*>(&LW[base + 44]);
                    int4 q2 = *reinterpret_cast<const int4*>(&LW[base + 1760]);
                    int4 q3 = *reinterpret_cast<const int4*>(&LW[base + 1804]);
                    bf16x8 b = bilerp(wt, q0, q1, q2, q3);
                    #pragma unroll
                    for (int mt = 0; mt < 4; ++mt)
                        acc[mt][nf] = __builtin_amdgcn_mfma_f32_16x16x32_bf16(
                                          a4[mt], b, acc[mt][nf], 0, 0, 0);
                }
            }
        }
    } else {
        // -------- slow path: global gathers (correct for any offsets) -----
        int px = tid >> 2, chq = tid & 3;
        int sbw = px*44 + chq*8;
        int bb[4];
        #pragma unroll
        for (int nf = 0; nf < 4; ++nf)
            bb[nf] = (nf*16 + l15)*44 + colq*8;
        for (int cc2 = 0; cc2 < 8; ++cc2) {
            for (int tap = 0; tap < 9; ++tap) {
                int kc = cc2*9 + tap;
                loadA(kc);
                int r = tap*64 + px;
                int4 o4 = cofsS[r];
                float4 wt = wtab[r];
                int c0 = cc2*32 + chq*8;
                int4 q0 = *reinterpret_cast<const int4*>(src + o4.x + c0);
                int4 q1 = *reinterpret_cast<const int4*>(src + o4.y + c0);
                int4 q2 = *reinterpret_cast<const int4*>(src + o4.z + c0);
                int4 q3 = *reinterpret_cast<const int4*>(src + o4.w + c0);
                bf16x8 bv = bilerp(wt, q0, q1, q2, q3);
                union { bf16x8 b8; int4 i4; } cv; cv.b8 = bv;
                __syncthreads();             // prev readers done
                *reinterpret_cast<int4*>(&SBs[sbw]) = cv.i4;
                __syncthreads();             // SB ready
                #pragma unroll
                for (int nf = 0; nf < 4; ++nf) {
                    bf16x8 b = *reinterpret_cast<const bf16x8*>(&SBs[bb[nf]]);
                    #pragma unroll
                    for (int mt = 0; mt < 4; ++mt)
                        acc[mt][nf] = __builtin_amdgcn_mfma_f32_16x16x32_bf16(
                                          apf[mt], b, acc[mt][nf], 0, 0, 0);
                }
            }
        }
    }

    // epilogue: LDS transpose -> coalesced NHWC writes. TO = [32 px][264]
    __syncthreads();
    u16* TO = LW;
    u16* aligp = alig + (size_t)n * PLANE;
    #pragma unroll
    for (int h = 0; h < 2; ++h) {
        #pragma unroll
        for (int sub = 0; sub < 2; ++sub) {
            int nf = 2*h + sub;
            int pl = sub*16 + l15;
            #pragma unroll
            for (int mt = 0; mt < 4; ++mt) {
                int o = (w*4+mt)*16 + colq*4;
                ushort4 v;
                v.x = f2bf(acc[mt][nf][0] + ab[o]);
                v.y = f2bf(acc[mt][nf][1] + ab[o+1]);
                v.z = f2bf(acc[mt][nf][2] + ab[o+2]);
                v.w = f2bf(acc[mt][nf][3] + ab[o+3]);
                *reinterpret_cast<ushort4*>(&TO[pl*264 + o]) = v;
            }
        }
        __syncthreads();
        #pragma unroll
        for (int it = 0; it < 4; ++it) {
            int i = tid + it*256;
            int pr = i >> 5, ck = i & 31;
            int nf = 2*h + (pr >> 4);
            int pxx = nf*16 + (pr & 15);
            int gp = (ty0 + (pxx>>5))*WW + tx0 + (pxx & 31);
            *reinterpret_cast<int4*>(aligp + (size_t)gp*CH + ck*8) =
                *reinterpret_cast<const int4*>(&TO[pr*264 + ck*8]);
        }
        __syncthreads();
    }
}

// ---------------------------------------------------------------------------
// fuse: softmax over N of g, weighted sum of alig (NHWC bf16), +emb, residual.
__global__ __launch_bounds__(256) void k_fuse_nhwc(
    const float* __restrict__ cur, const u16* __restrict__ alig,
    const float* __restrict__ g, const float* __restrict__ emb,
    float* __restrict__ out)
{
    int p0 = blockIdx.x * 32;
    int tid = threadIdx.x;
    __shared__ float wE[NN][32];
    __shared__ float trans[256][33];

    if (tid < 32) {
        int p = p0 + tid;
        float e[NN], m = -1e30f;
        #pragma unroll
        for (int n = 0; n < NN; ++n) { e[n] = g[n*HWSZ + p]; m = fmaxf(m, e[n]); }
        float se = 0.f;
        #pragma unroll
        for (int n = 0; n < NN; ++n) { e[n] = expf(e[n] - m); se += e[n]; }
        float inv = 1.f / se;
        #pragma unroll
        for (int n = 0; n < NN; ++n) wE[n][tid] = e[n] * inv;
    }
    __syncthreads();

    #pragma unroll
    for (int it = 0; it < 4; ++it) {
        int i = tid + it*256;
        int px = i >> 5, ck = i & 31;
        float a8[8];
        #pragma unroll
        for (int j = 0; j < 8; ++j) a8[j] = 0.f;
        #pragma unroll
        for (int n = 0; n < NN; ++n) {
            int4 v = *reinterpret_cast<const int4*>(
                &alig[((size_t)n*HWSZ + p0 + px)*CH + ck*8]);
            float f = wE[n][px];
            #pragma unroll
            for (int j4 = 0; j4 < 4; ++j4) {
                u32 u = ((const u32*)&v)[j4];
                a8[2*j4]   += bflo(u) * f;
                a8[2*j4+1] += bfhi(u) * f;
            }
        }
        #pragma unroll
        for (int j = 0; j < 8; ++j) {
            int c = ck*8 + j;
            trans[c][px ^ (c & 31)] = a8[j] + emb[c];
        }
    }
    __syncthreads();
    for (int it = 0; it < 32; ++it) {
        int c = (tid >> 5) + it*8, px = tid & 31;
        int idx = c*HWSZ + p0 + px;
        out[idx] = cur[idx] + 0.5f * trans[c][px ^ (c & 31)];
    }
}

// ---------------------------------------------------------------------------
extern "C" void kernel_launch(void* const* d_in, const int* in_sizes, int n_in,
                              void* d_out, int out_size, void* d_ws, size_t ws_size,
                              hipStream_t stream)
{
    const float* cur = (const float*)d_in[0];
    const float* nbr = (const float*)d_in[1];
    const float* cd  = (const float*)d_in[2];
    const float* aw  = (const float*)d_in[3];
    const float* ab  = (const float*)d_in[4];
    const float* ow  = (const float*)d_in[5];
    const float* ob  = (const float*)d_in[6];
    const float* g1w = (const float*)d_in[7];
    const float* g1b = (const float*)d_in[8];
    const float* g2w = (const float*)d_in[9];
    const float* g2b = (const float*)d_in[10];
    const float* ew  = (const float*)d_in[11];
    const float* eb  = (const float*)d_in[12];
    float* out = (float*)d_out;
    float* ws  = (float*)d_ws;

    float* offs = ws;                          // 1,327,104 f
    float* gbuf = offs + 1327104;              // 73,728 f
    float* emb  = gbuf + 73728;                // 256 f
    u16* nbrh = (u16*)(emb + 256);             // 8 * PLANE
    u16* curh = nbrh + (size_t)NN*PLANE;       // PLANE
    u16* alig = curh + PLANE;                  // 8 * PLANE (NHWC)
    u16* wpO  = alig + (size_t)NN*PLANE;       // 32*4608
    u16* wpG  = wpO + 147456;                  // 128*4608
    u16* wpA  = wpG + 589824;                  // 256*2304

    k_emb_sum<<<dim3(1), dim3(256), 0, stream>>>(cd, ew, eb, emb);
    k_to_nhwc<<<dim3(144, 8), dim3(256), 0, stream>>>(nbr, nbrh);
    k_to_nhwc<<<dim3(144, 1), dim3(256), 0, stream>>>(cur, curh);
    k_pack_w<<<dim3((32*4608 + 255)/256), dim3(256), 0, stream>>>(ow, wpO, 18, 32, 512, 0);
    k_pack_w<<<dim3((128*4608 + 255)/256), dim3(256), 0, stream>>>(g1w, wpG, 128, 128, 512, 0);
    k_pack_w<<<dim3((256*2304 + 255)/256), dim3(256), 0, stream>>>(aw, wpA, 256, 256, 256, 1);

    // offset conv: concat(nbr_n, cur) -> 18 ch (padded to 32), XCD-pinned n
    k_conv_nhwc<1, 0><<<dim3(8, 36), dim3(512), 0, stream>>>(
        nbrh, (long)PLANE, curh, 0L, wpO, ob, nullptr, nullptr, offs);
    // deformable conv -> alig (NHWC bf16), XCD-pinned n, windowed barrier-free
    k_deform_nhwc<<<dim3(8, 144), dim3(256), 0, stream>>>(nbrh, offs, wpA, ab, alig);
    // gate: concat(cur, alig_n) -> 128 -> relu -> 1x1 -> sigmoid, XCD-pinned n
    k_conv_nhwc<4, 1><<<dim3(8, 36), dim3(512), 0, stream>>>(
        curh, 0L, alig, (long)PLANE, wpG, g1b, g2w, g2b, gbuf);
    // softmax + fuse + residual
    k_fuse_nhwc<<<dim3(288), dim3(256), 0, stream>>>(cur, alig, gbuf, emb, out);
}

// Round 13
// 407.542 us; speedup vs baseline: 2.2123x; 2.2123x over previous
//
#include <hip/hip_runtime.h>
#include <math.h>

// Problem constants: B=1, C=256, H=96, W=96, N=8
#define CH   256
#define HH   96
#define WW   96
#define NN   8
#define HWSZ 9216
#define PLANE (HWSZ*CH)          // elements per neighbor in NHWC

typedef unsigned short u16;
typedef unsigned int   u32;
typedef short bf16x8 __attribute__((ext_vector_type(8)));
typedef float f32x4  __attribute__((ext_vector_type(4)));
typedef float f32x2  __attribute__((ext_vector_type(2)));

__device__ inline u16 f2bf(float f) {
    union { float f; u32 u; } v; v.f = f;
    u32 r = v.u + 0x7FFF + ((v.u >> 16) & 1);   // RNE
    return (u16)(r >> 16);
}
__device__ inline float bflo(u32 u) {
    union { u32 u; float f; } v; v.u = u << 16; return v.f;
}
__device__ inline float bfhi(u32 u) {
    union { u32 u; float f; } v; v.u = u & 0xffff0000u; return v.f;
}
__device__ inline u32 pk2bf(float lo, float hi) {   // RNE pack pair
    union { float f; u32 u; } a, b; a.f = lo; b.f = hi;
    u32 ra = a.u + 0x7FFF + ((a.u >> 16) & 1);
    u32 rb = b.u + 0x7FFF + ((b.u >> 16) & 1);
    return (ra >> 16) | (rb & 0xffff0000u);
}

// ---------------------------------------------------------------------------
__global__ void k_emb_sum(const float* __restrict__ cd,
                          const float* __restrict__ enc_w,
                          const float* __restrict__ enc_b,
                          float* __restrict__ emb)
{
    int c = threadIdx.x;
    float s = 0.f;
    for (int n = 0; n < NN; ++n) {
        float d = enc_b[c];
        #pragma unroll
        for (int j = 0; j < 4; ++j) d += cd[n*4 + j] * enc_w[c*4 + j];
        s += d;
    }
    emb[c] = s;
}

// ---------------------------------------------------------------------------
// NCHW f32 -> NHWC bf16 via LDS transpose; both sides coalesced.
// grid (144, N), block 256: 64 px x 256 ch per block.
__global__ __launch_bounds__(256) void k_to_nhwc(const float* __restrict__ in,
                                                 u16* __restrict__ out)
{
    int n = blockIdx.y;
    int p0 = blockIdx.x * 64;
    int tid = threadIdx.x;
    __shared__ u16 T[64][262];

    int px4 = (tid & 15) * 4, cb = tid >> 4;
    for (int it = 0; it < 16; ++it) {
        int c = cb + it*16;
        float4 v = *reinterpret_cast<const float4*>(
            in + ((size_t)n*CH + c)*HWSZ + p0 + px4);
        T[px4+0][c] = f2bf(v.x);
        T[px4+1][c] = f2bf(v.y);
        T[px4+2][c] = f2bf(v.z);
        T[px4+3][c] = f2bf(v.w);
    }
    __syncthreads();
    int pxb = tid >> 5, ck = tid & 31;
    for (int it = 0; it < 8; ++it) {
        int p = pxb + it*8;
        *reinterpret_cast<int4*>(out + (size_t)n*PLANE + (size_t)(p0+p)*CH + ck*8) =
            *reinterpret_cast<const int4*>(&T[p][ck*8]);
    }
}

// ---------------------------------------------------------------------------
// pack conv weights w[O][CIN][3][3] (fp32 OIHW) -> bf16 A-fragment layout.
// K = tap*CIN + c (tap-major); kc = K>>5.
// Wp[o>>4][kc][lane][8], lane = ((K&31)>>3)*16 + (o&15), j = K&7.
__global__ void k_pack_w(const float* __restrict__ w, u16* __restrict__ wp,
                         int O, int O_pad, int CIN)
{
    int idx = blockIdx.x * 256 + threadIdx.x;
    int total = O_pad * CIN * 9;
    if (idx >= total) return;
    int o = idx / (CIN * 9);
    int K = idx % (CIN * 9);
    int tap = K / CIN, c = K % CIN;
    float v = (o < O) ? w[((size_t)o * CIN + c) * 9 + tap] : 0.f;
    int NKC = (CIN * 9) >> 5;
    int kc = K >> 5, kl = K & 31;
    int lane = (kl >> 3) * 16 + (o & 15);
    size_t dstp = (((size_t)(o >> 4) * NKC + kc) * 64 + lane) * 8 + (kl & 7);
    wp[dstp] = f2bf(v);
}

// ---------------------------------------------------------------------------
// shift-conv 3x3 pad1 on concat(in0_n, in1_n) (512 in-ch, NHWC bf16) via MFMA.
// tile 8 rows x 32 cols (256 px), grid (8, 36) [XCD-pinned n], block 512.
// EPI 0: store fp32 planes (o<18) -> offs. EPI 1: gate epilogue -> gbuf.
template<int MTW, int EPI>
__global__ __launch_bounds__(512) void k_conv_nhwc(
    const u16* __restrict__ in0, long s0,
    const u16* __restrict__ in1, long s1,
    const u16* __restrict__ Wp, const float* __restrict__ b1,
    const float* __restrict__ g2w, const float* __restrict__ g2b,
    float* __restrict__ out)
{
    constexpr int NKC = 144, NCC = 16;
    int n = blockIdx.x, t = blockIdx.y;
    int tx0 = (t % 3) * 32, ty0 = (t / 3) * 8;
    int tid = threadIdx.x, lane = tid & 63, w = tid >> 6;
    int mh = w >> 2, pg = w & 3;
    int colq = lane >> 4;

    __shared__ __align__(16) u16 SB[340*40];
    __shared__ float gpart[8][64];

    f32x4 acc[MTW][4];
    #pragma unroll
    for (int mt = 0; mt < MTW; ++mt)
        #pragma unroll
        for (int nf = 0; nf < 4; ++nf)
            acc[mt][nf] = (f32x4){0.f,0.f,0.f,0.f};

    int bidx[4];
    #pragma unroll
    for (int nf = 0; nf < 4; ++nf) {
        int px = pg*64 + nf*16 + (lane & 15);
        int row = px >> 5, col = px & 31;
        bidx[nf] = ((row+1)*34 + (col+1))*40 + colq*8;
    }

    for (int cc = 0; cc < NCC; ++cc) {
        const u16* base = (cc < 8) ? in0 + (size_t)n*s0 + cc*32
                                   : in1 + (size_t)n*s1 + (cc-8)*32;
        for (int i = tid; i < 1360; i += 512) {
            int ph = i >> 2, q = i & 3;
            int r = ph / 34, col = ph - r*34;
            int y = ty0 - 1 + r, x = tx0 - 1 + col;
            bool v = ((unsigned)y < (unsigned)HH) && ((unsigned)x < (unsigned)WW);
            int off = v ? (y*WW + x)*CH : 0;
            int4 val = *reinterpret_cast<const int4*>(base + off + q*8);
            if (!v) val = make_int4(0,0,0,0);
            *reinterpret_cast<int4*>(&SB[ph*40 + q*8]) = val;
        }
        __syncthreads();
        #pragma unroll
        for (int tap = 0; tap < 9; ++tap) {
            int kc = tap*NCC + cc;
            bf16x8 a[MTW];
            #pragma unroll
            for (int mt = 0; mt < MTW; ++mt)
                a[mt] = *reinterpret_cast<const bf16x8*>(
                    Wp + (((size_t)(mh*MTW+mt)*NKC + kc)*64 + lane)*8);
            const int dy = tap/3 - 1, dx = tap%3 - 1;
            #pragma unroll
            for (int nf = 0; nf < 4; ++nf) {
                bf16x8 b = *reinterpret_cast<const bf16x8*>(
                    &SB[bidx[nf] + (dy*34 + dx)*40]);
                #pragma unroll
                for (int mt = 0; mt < MTW; ++mt)
                    acc[mt][nf] = __builtin_amdgcn_mfma_f32_16x16x32_bf16(
                                      a[mt], b, acc[mt][nf], 0, 0, 0);
            }
        }
        __syncthreads();
    }

    if (EPI == 0) {
        #pragma unroll
        for (int nf = 0; nf < 4; ++nf) {
            int px = pg*64 + nf*16 + (lane & 15);
            int gp = (ty0 + (px>>5))*WW + tx0 + (px & 31);
            #pragma unroll
            for (int mt = 0; mt < MTW; ++mt) {
                int o_base = (mh*MTW+mt)*16 + colq*4;
                #pragma unroll
                for (int r = 0; r < 4; ++r) {
                    int o = o_base + r;
                    if (o < 18)
                        out[((size_t)n*18 + o)*HWSZ + gp] = acc[mt][nf][r] + b1[o];
                }
            }
        }
    } else {
        float part[4];
        #pragma unroll
        for (int nf = 0; nf < 4; ++nf) {
            float s = 0.f;
            #pragma unroll
            for (int mt = 0; mt < MTW; ++mt) {
                int o_base = (mh*MTW+mt)*16 + colq*4;
                #pragma unroll
                for (int r = 0; r < 4; ++r) {
                    int o = o_base + r;
                    float vv = fmaxf(acc[mt][nf][r] + b1[o], 0.f);
                    s += vv * g2w[o];
                }
            }
            part[nf] = s;
        }
        #pragma unroll
        for (int nf = 0; nf < 4; ++nf) {
            part[nf] += __shfl_xor(part[nf], 16, 64);
            part[nf] += __shfl_xor(part[nf], 32, 64);
        }
        if (lane < 16) {
            #pragma unroll
            for (int nf = 0; nf < 4; ++nf)
                gpart[w][nf*16 + lane] = part[nf];
        }
        __syncthreads();
        if (tid < 256) {
            int pxl = tid & 63, pgg = tid >> 6;
            float s = gpart[pgg][pxl] + gpart[4 + pgg][pxl] + g2b[0];
            float g = 1.f / (1.f + expf(-s));
            int px = pgg*64 + pxl;
            int gp = (ty0 + (px>>5))*WW + tx0 + (px & 31);
            out[(size_t)n*HWSZ + gp] = g;
        }
    }
}

// ---------------------------------------------------------------------------
// deformable 3x3 conv via bf16 MFMA, NHWC in/out — byte-exact revert to the
// best-measured variant (197 us, round-5 bench): tile 2 rows x 32 cols,
// grid (8, 144) [XCD-pinned n], block 256 = 4 waves; wave w owns 64 oc.
// 4-thread quad per pixel (coalesced 64B corner segments), depth-1 prefetch,
// per-kc validity recompute (the VALU fills latency slots), stride-40 SB,
// plain __syncthreads.  All measured "fixes" (stride-44, hoisted VALU,
// depth-2, role-split, windows, FASTBAR) were neutral-to-negative.
__global__ __launch_bounds__(256) void k_deform_nhwc(
    const u16* __restrict__ nbrh, const float* __restrict__ offs,
    const u16* __restrict__ Wp, const float* __restrict__ ab,
    u16* __restrict__ alig)
{
    constexpr int NKC = 72;
    int n = blockIdx.x, t = blockIdx.y;
    int tx0 = (t % 3) * 32, ty0 = (t / 3) * 2;
    int tid = threadIdx.x, lane = tid & 63, w = tid >> 6;
    int colq = lane >> 4;

    __shared__ __align__(16) u16 pool[8448];      // SBm[2][2560] | TO[32][264]
    __shared__ u32   cpos[576];
    __shared__ float cwy[576], cwx[576];
    u16* SB0 = pool;
    u16* SB1 = pool + 2560;

    const u16* src = nbrh + (size_t)n * PLANE;

    for (int i = tid; i < 576; i += 256) {
        int tt = i >> 6, px = i & 63;
        int y = ty0 + (px>>5), x = tx0 + (px & 31);
        int pp = y*WW + x;
        float oy = offs[((size_t)n*18 + 2*tt    )*HWSZ + pp];
        float ox = offs[((size_t)n*18 + 2*tt + 1)*HWSZ + pp];
        float py  = (float)y + (float)(tt/3 - 1) + oy;
        float pxx = (float)x + (float)(tt%3 - 1) + ox;
        py  = fminf(fmaxf(py,  -4.f), 100.f);
        pxx = fminf(fmaxf(pxx, -4.f), 100.f);
        float y0f = floorf(py), x0f = floorf(pxx);
        cpos[i] = ((u32)((int)y0f + 4) << 16) | (u32)((int)x0f + 4);
        cwy[i] = py - y0f; cwx[i] = pxx - x0f;
    }
    __syncthreads();

    f32x4 acc[4][4];
    #pragma unroll
    for (int mt = 0; mt < 4; ++mt)
        #pragma unroll
        for (int nf = 0; nf < 4; ++nf)
            acc[mt][nf] = (f32x4){0.f,0.f,0.f,0.f};

    int px = tid >> 2, chq = tid & 3;            // produce mapping
    int sbw = px*40 + chq*8;
    int bb[4];
    #pragma unroll
    for (int nf = 0; nf < 4; ++nf)
        bb[nf] = (nf*16 + (lane & 15))*40 + colq*8;

    auto loadC = [&](int kc, int4* q) {
        int tt = kc >> 3, cc = kc & 7;
        int r = (tt<<6) + px;
        u32 cp = cpos[r];
        int y0 = (int)(cp >> 16) - 4, x0 = (int)(cp & 0xffff) - 4;
        bool y0i = (y0 >= 0) & (y0 < HH);
        bool y1i = (y0 >= -1) & (y0 < HH-1);
        bool x0i = (x0 >= 0) & (x0 < WW);
        bool x1i = (x0 >= -1) & (x0 < WW-1);
        int c0 = cc*32 + chq*8;
        int a00 = (y0*WW + x0)*CH + c0;
        int o00 = (y0i & x0i) ? a00            : 0;
        int o01 = (y0i & x1i) ? a00 + CH       : 0;
        int o10 = (y1i & x0i) ? a00 + WW*CH    : 0;
        int o11 = (y1i & x1i) ? a00 + WW*CH+CH : 0;
        int4 z = make_int4(0,0,0,0);
        int4 q0 = *reinterpret_cast<const int4*>(src + o00);
        int4 q1 = *reinterpret_cast<const int4*>(src + o01);
        int4 q2 = *reinterpret_cast<const int4*>(src + o10);
        int4 q3 = *reinterpret_cast<const int4*>(src + o11);
        q[0] = (y0i & x0i) ? q0 : z;
        q[1] = (y0i & x1i) ? q1 : z;
        q[2] = (y1i & x0i) ? q2 : z;
        q[3] = (y1i & x1i) ? q3 : z;
    };
    auto bilerp = [&](int kc, const int4* q) -> int4 {
        int r = ((kc >> 3)<<6) + px;
        float wy = cwy[r], wx = cwx[r];
        float w00 = (1.f-wy)*(1.f-wx), w01 = (1.f-wy)*wx;
        float w10 = wy*(1.f-wx),       w11 = wy*wx;
        int4 res;
        #pragma unroll
        for (int j = 0; j < 4; ++j) {
            u32 u00 = ((const u32*)&q[0])[j], u01 = ((const u32*)&q[1])[j];
            u32 u10 = ((const u32*)&q[2])[j], u11 = ((const u32*)&q[3])[j];
            float lo = w00*bflo(u00) + w01*bflo(u01) + w10*bflo(u10) + w11*bflo(u11);
            float hi = w00*bfhi(u00) + w01*bfhi(u01) + w10*bfhi(u10) + w11*bfhi(u11);
            ((u32*)&res)[j] = pk2bf(lo, hi);
        }
        return res;
    };
    auto loadA = [&](int kc, bf16x8* a) {
        #pragma unroll
        for (int mt = 0; mt < 4; ++mt)
            a[mt] = *reinterpret_cast<const bf16x8*>(
                Wp + (((size_t)(w*4+mt)*NKC + kc)*64 + lane)*8);
    };

    int4 crn[4];
    bf16x8 apf[4];
    loadC(0, crn);
    loadA(0, apf);
    int cur = 0;
    for (int kc = 0; kc < NKC; ++kc) {
        int4 vpk = bilerp(kc, crn);
        u16* SBc = cur ? SB1 : SB0;
        *reinterpret_cast<int4*>(&SBc[sbw]) = vpk;
        bf16x8 a4[4];
        #pragma unroll
        for (int mt = 0; mt < 4; ++mt) a4[mt] = apf[mt];
        if (kc + 1 < NKC) { loadC(kc + 1, crn); loadA(kc + 1, apf); }  // T14
        __syncthreads();
        #pragma unroll
        for (int nf = 0; nf < 4; ++nf) {
            bf16x8 b = *reinterpret_cast<const bf16x8*>(&SBc[bb[nf]]);
            #pragma unroll
            for (int mt = 0; mt < 4; ++mt)
                acc[mt][nf] = __builtin_amdgcn_mfma_f32_16x16x32_bf16(
                                  a4[mt], b, acc[mt][nf], 0, 0, 0);
        }
        cur ^= 1;
    }

    // epilogue: LDS transpose -> coalesced NHWC writes. TO = [32 px][264]
    __syncthreads();
    u16* TO = pool;
    u16* aligp = alig + (size_t)n * PLANE;
    #pragma unroll
    for (int h = 0; h < 2; ++h) {
        #pragma unroll
        for (int sub = 0; sub < 2; ++sub) {
            int nf = 2*h + sub;
            int pl = sub*16 + (lane & 15);
            #pragma unroll
            for (int mt = 0; mt < 4; ++mt) {
                int o = (w*4+mt)*16 + colq*4;
                ushort4 v;
                v.x = f2bf(acc[mt][nf][0] + ab[o]);
                v.y = f2bf(acc[mt][nf][1] + ab[o+1]);
                v.z = f2bf(acc[mt][nf][2] + ab[o+2]);
                v.w = f2bf(acc[mt][nf][3] + ab[o+3]);
                *reinterpret_cast<ushort4*>(&TO[pl*264 + o]) = v;
            }
        }
        __syncthreads();
        #pragma unroll
        for (int it = 0; it < 4; ++it) {
            int i = tid + it*256;
            int pr = i >> 5, ck = i & 31;
            int nf = 2*h + (pr >> 4);
            int pxx = nf*16 + (pr & 15);
            int gp = (ty0 + (pxx>>5))*WW + tx0 + (pxx & 31);
            *reinterpret_cast<int4*>(aligp + (size_t)gp*CH + ck*8) =
                *reinterpret_cast<const int4*>(&TO[pr*264 + ck*8]);
        }
        __syncthreads();
    }
}

// ---------------------------------------------------------------------------
// fuse: softmax over N of g, weighted sum of alig (NHWC bf16), +emb, residual.
__global__ __launch_bounds__(256) void k_fuse_nhwc(
    const float* __restrict__ cur, const u16* __restrict__ alig,
    const float* __restrict__ g, const float* __restrict__ emb,
    float* __restrict__ out)
{
    int p0 = blockIdx.x * 32;
    int tid = threadIdx.x;
    __shared__ float wE[NN][32];
    __shared__ float trans[256][33];

    if (tid < 32) {
        int p = p0 + tid;
        float e[NN], m = -1e30f;
        #pragma unroll
        for (int n = 0; n < NN; ++n) { e[n] = g[n*HWSZ + p]; m = fmaxf(m, e[n]); }
        float se = 0.f;
        #pragma unroll
        for (int n = 0; n < NN; ++n) { e[n] = expf(e[n] - m); se += e[n]; }
        float inv = 1.f / se;
        #pragma unroll
        for (int n = 0; n < NN; ++n) wE[n][tid] = e[n] * inv;
    }
    __syncthreads();

    #pragma unroll
    for (int it = 0; it < 4; ++it) {
        int i = tid + it*256;
        int px = i >> 5, ck = i & 31;
        float a8[8];
        #pragma unroll
        for (int j = 0; j < 8; ++j) a8[j] = 0.f;
        #pragma unroll
        for (int n = 0; n < NN; ++n) {
            int4 v = *reinterpret_cast<const int4*>(
                &alig[((size_t)n*HWSZ + p0 + px)*CH + ck*8]);
            float f = wE[n][px];
            #pragma unroll
            for (int j4 = 0; j4 < 4; ++j4) {
                u32 u = ((const u32*)&v)[j4];
                a8[2*j4]   += bflo(u) * f;
                a8[2*j4+1] += bfhi(u) * f;
            }
        }
        #pragma unroll
        for (int j = 0; j < 8; ++j) {
            int c = ck*8 + j;
            trans[c][px ^ (c & 31)] = a8[j] + emb[c];
        }
    }
    __syncthreads();
    for (int it = 0; it < 32; ++it) {
        int c = (tid >> 5) + it*8, px = tid & 31;
        int idx = c*HWSZ + p0 + px;
        out[idx] = cur[idx] + 0.5f * trans[c][px ^ (c & 31)];
    }
}

// ---------------------------------------------------------------------------
extern "C" void kernel_launch(void* const* d_in, const int* in_sizes, int n_in,
                              void* d_out, int out_size, void* d_ws, size_t ws_size,
                              hipStream_t stream)
{
    const float* cur = (const float*)d_in[0];
    const float* nbr = (const float*)d_in[1];
    const float* cd  = (const float*)d_in[2];
    const float* aw  = (const float*)d_in[3];
    const float* ab  = (const float*)d_in[4];
    const float* ow  = (const float*)d_in[5];
    const float* ob  = (const float*)d_in[6];
    const float* g1w = (const float*)d_in[7];
    const float* g1b = (const float*)d_in[8];
    const float* g2w = (const float*)d_in[9];
    const float* g2b = (const float*)d_in[10];
    const float* ew  = (const float*)d_in[11];
    const float* eb  = (const float*)d_in[12];
    float* out = (float*)d_out;
    float* ws  = (float*)d_ws;

    float* offs = ws;                          // 1,327,104 f
    float* gbuf = offs + 1327104;              // 73,728 f
    float* emb  = gbuf + 73728;                // 256 f
    u16* nbrh = (u16*)(emb + 256);             // 8 * PLANE
    u16* curh = nbrh + (size_t)NN*PLANE;       // PLANE
    u16* alig = curh + PLANE;                  // 8 * PLANE (NHWC)
    u16* wpO  = alig + (size_t)NN*PLANE;       // 32*4608
    u16* wpG  = wpO + 147456;                  // 128*4608
    u16* wpA  = wpG + 589824;                  // 256*2304

    k_emb_sum<<<dim3(1), dim3(256), 0, stream>>>(cd, ew, eb, emb);
    k_to_nhwc<<<dim3(144, 8), dim3(256), 0, stream>>>(nbr, nbrh);
    k_to_nhwc<<<dim3(144, 1), dim3(256), 0, stream>>>(cur, curh);
    k_pack_w<<<dim3((32*4608 + 255)/256), dim3(256), 0, stream>>>(ow, wpO, 18, 32, 512);
    k_pack_w<<<dim3((128*4608 + 255)/256), dim3(256), 0, stream>>>(g1w, wpG, 128, 128, 512);
    k_pack_w<<<dim3((256*2304 + 255)/256), dim3(256), 0, stream>>>(aw, wpA, 256, 256, 256);

    // offset conv: concat(nbr_n, cur) -> 18 ch (padded to 32), XCD-pinned n
    k_conv_nhwc<1, 0><<<dim3(8, 36), dim3(512), 0, stream>>>(
        nbrh, (long)PLANE, curh, 0L, wpO, ob, nullptr, nullptr, offs);
    // deformable conv -> alig (NHWC bf16), XCD-pinned n
    k_deform_nhwc<<<dim3(8, 144), dim3(256), 0, stream>>>(nbrh, offs, wpA, ab, alig);
    // gate: concat(cur, alig_n) -> 128 -> relu -> 1x1 -> sigmoid, XCD-pinned n
    k_conv_nhwc<4, 1><<<dim3(8, 36), dim3(512), 0, stream>>>(
        curh, 0L, alig, (long)PLANE, wpG, g1b, g2w, g2b, gbuf);
    // softmax + fuse + residual
    k_fuse_nhwc<<<dim3(288), dim3(256), 0, stream>>>(cur, alig, gbuf, emb, out);
}

// Round 14
// 380.019 us; speedup vs baseline: 2.3725x; 1.0724x over previous
//
#include <hip/hip_runtime.h>
#include <math.h>

// Problem constants: B=1, C=256, H=96, W=96, N=8
#define CH   256
#define HH   96
#define WW   96
#define NN   8
#define HWSZ 9216
#define PLANE (HWSZ*CH)          // elements per neighbor in NHWC

typedef unsigned short u16;
typedef unsigned int   u32;
typedef short bf16x8 __attribute__((ext_vector_type(8)));
typedef float f32x4  __attribute__((ext_vector_type(4)));
typedef float f32x2  __attribute__((ext_vector_type(2)));

__device__ inline u16 f2bf(float f) {
    union { float f; u32 u; } v; v.f = f;
    u32 r = v.u + 0x7FFF + ((v.u >> 16) & 1);   // RNE
    return (u16)(r >> 16);
}
__device__ inline float bflo(u32 u) {
    union { u32 u; float f; } v; v.u = u << 16; return v.f;
}
__device__ inline float bfhi(u32 u) {
    union { u32 u; float f; } v; v.u = u & 0xffff0000u; return v.f;
}
__device__ inline u32 pk2bf(float lo, float hi) {   // RNE pack pair
    union { float f; u32 u; } a, b; a.f = lo; b.f = hi;
    u32 ra = a.u + 0x7FFF + ((a.u >> 16) & 1);
    u32 rb = b.u + 0x7FFF + ((b.u >> 16) & 1);
    return (ra >> 16) | (rb & 0xffff0000u);
}

// ---------------------------------------------------------------------------
__global__ void k_emb_sum(const float* __restrict__ cd,
                          const float* __restrict__ enc_w,
                          const float* __restrict__ enc_b,
                          float* __restrict__ emb)
{
    int c = threadIdx.x;
    float s = 0.f;
    for (int n = 0; n < NN; ++n) {
        float d = enc_b[c];
        #pragma unroll
        for (int j = 0; j < 4; ++j) d += cd[n*4 + j] * enc_w[c*4 + j];
        s += d;
    }
    emb[c] = s;
}

// ---------------------------------------------------------------------------
// NCHW f32 -> NHWC bf16 via LDS transpose; both sides coalesced.
// grid (144, 9): n<8 = neighbors, n==8 = current frame (curh follows nbrh).
__global__ __launch_bounds__(256) void k_to_nhwc(const float* __restrict__ nbr,
                                                 const float* __restrict__ cur,
                                                 u16* __restrict__ out)
{
    int n = blockIdx.y;
    const float* src = (n < 8) ? nbr + (size_t)n * CH * HWSZ : cur;
    int p0 = blockIdx.x * 64;
    int tid = threadIdx.x;
    __shared__ u16 T[64][262];

    int px4 = (tid & 15) * 4, cb = tid >> 4;
    for (int it = 0; it < 16; ++it) {
        int c = cb + it*16;
        float4 v = *reinterpret_cast<const float4*>(
            src + (size_t)c*HWSZ + p0 + px4);
        T[px4+0][c] = f2bf(v.x);
        T[px4+1][c] = f2bf(v.y);
        T[px4+2][c] = f2bf(v.z);
        T[px4+3][c] = f2bf(v.w);
    }
    __syncthreads();
    int pxb = tid >> 5, ck = tid & 31;
    for (int it = 0; it < 8; ++it) {
        int p = pxb + it*8;
        *reinterpret_cast<int4*>(out + (size_t)n*PLANE + (size_t)(p0+p)*CH + ck*8) =
            *reinterpret_cast<const int4*>(&T[p][ck*8]);
    }
}

// ---------------------------------------------------------------------------
// pack conv weights w[O][CIN][3][3] (fp32 OIHW) -> bf16 A-fragment layout.
// K = tap*CIN + c (tap-major); kc = K>>5.
__global__ void k_pack_w(const float* __restrict__ w, u16* __restrict__ wp,
                         int O, int O_pad, int CIN)
{
    int idx = blockIdx.x * 256 + threadIdx.x;
    int total = O_pad * CIN * 9;
    if (idx >= total) return;
    int o = idx / (CIN * 9);
    int K = idx % (CIN * 9);
    int tap = K / CIN, c = K % CIN;
    float v = (o < O) ? w[((size_t)o * CIN + c) * 9 + tap] : 0.f;
    int NKC = (CIN * 9) >> 5;
    int kc = K >> 5, kl = K & 31;
    int lane = (kl >> 3) * 16 + (o & 15);
    size_t dstp = (((size_t)(o >> 4) * NKC + kc) * 64 + lane) * 8 + (kl & 7);
    wp[dstp] = f2bf(v);
}

// ---------------------------------------------------------------------------
// shift-conv 3x3 pad1 on concat(in0_n, in1_n) (512 in-ch, NHWC bf16) via MFMA.
// tile 4 rows x 32 cols (128 px), grid (8, 72) [XCD-pinned n].
// NW = NMH*2 waves: mh = w>>1 (M-group), pg = w&1 (64-px group).
// T14 async-STAGE: next chunk's global loads issued right after the SB-ready
// barrier so they fly under the 9-tap MFMA phase; reg->LDS store lands after
// the readers-done barrier (vmcnt already satisfied by then).
// EPI 0: store fp32 planes (o<18) -> offs. EPI 1: gate epilogue -> gbuf.
template<int MTW, int NMH, int EPI>
__global__ __launch_bounds__(NMH*128) void k_conv_nhwc(
    const u16* __restrict__ in0, long s0,
    const u16* __restrict__ in1, long s1,
    const u16* __restrict__ Wp, const float* __restrict__ b1,
    const float* __restrict__ g2w, const float* __restrict__ g2b,
    float* __restrict__ out)
{
    constexpr int NKC = 144, NCC = 16;
    constexpr int BS  = NMH * 128;            // block size
    constexpr int KK  = (816 + BS - 1) / BS;  // staging int4s per thread
    int n = blockIdx.x, t = blockIdx.y;
    int tx0 = (t % 3) * 32, ty0 = (t / 3) * 4;
    int tid = threadIdx.x, lane = tid & 63, w = tid >> 6;
    int mh = w >> 1, pg = w & 1;
    int colq = lane >> 4;

    __shared__ __align__(16) u16 SB[204*40];  // 6x34 halo x 32ch, +pad stride
    __shared__ float gpart[8][64];

    f32x4 acc[MTW][4];
    #pragma unroll
    for (int mt = 0; mt < MTW; ++mt)
        #pragma unroll
        for (int nf = 0; nf < 4; ++nf)
            acc[mt][nf] = (f32x4){0.f,0.f,0.f,0.f};

    int bidx[4];
    #pragma unroll
    for (int nf = 0; nf < 4; ++nf) {
        int px = pg*64 + nf*16 + (lane & 15);
        int row = px >> 5, col = px & 31;
        bidx[nf] = ((row+1)*34 + (col+1))*40 + colq*8;
    }

    int4 stg[KK];
    auto ldreg = [&](int cc) {
        const u16* base = (cc < 8) ? in0 + (size_t)n*s0 + cc*32
                                   : in1 + (size_t)n*s1 + (cc-8)*32;
        #pragma unroll
        for (int k = 0; k < KK; ++k) {
            int i = tid + k*BS;
            int4 v = make_int4(0,0,0,0);
            if (i < 816) {
                int ph = i >> 2, q = i & 3;
                int r = ph / 34, col = ph - r*34;
                int y = ty0 - 1 + r, x = tx0 - 1 + col;
                if (((unsigned)y < (unsigned)HH) && ((unsigned)x < (unsigned)WW))
                    v = *reinterpret_cast<const int4*>(base + (y*WW + x)*CH + q*8);
            }
            stg[k] = v;
        }
    };
    auto streg = [&]() {
        #pragma unroll
        for (int k = 0; k < KK; ++k) {
            int i = tid + k*BS;
            if (i < 816) {
                int ph = i >> 2, q = i & 3;
                *reinterpret_cast<int4*>(&SB[ph*40 + q*8]) = stg[k];
            }
        }
    };

    ldreg(0);
    for (int cc = 0; cc < NCC; ++cc) {
        __syncthreads();                      // readers done with SB
        streg();                              // write chunk cc
        __syncthreads();                      // SB ready
        if (cc + 1 < NCC) ldreg(cc + 1);      // T14: loads fly under MFMA phase
        #pragma unroll
        for (int tap = 0; tap < 9; ++tap) {
            int kc = tap*NCC + cc;
            bf16x8 a[MTW];
            #pragma unroll
            for (int mt = 0; mt < MTW; ++mt)
                a[mt] = *reinterpret_cast<const bf16x8*>(
                    Wp + (((size_t)(mh*MTW+mt)*NKC + kc)*64 + lane)*8);
            const int dy = tap/3 - 1, dx = tap%3 - 1;
            #pragma unroll
            for (int nf = 0; nf < 4; ++nf) {
                bf16x8 b = *reinterpret_cast<const bf16x8*>(
                    &SB[bidx[nf] + (dy*34 + dx)*40]);
                #pragma unroll
                for (int mt = 0; mt < MTW; ++mt)
                    acc[mt][nf] = __builtin_amdgcn_mfma_f32_16x16x32_bf16(
                                      a[mt], b, acc[mt][nf], 0, 0, 0);
            }
        }
    }

    if (EPI == 0) {
        #pragma unroll
        for (int nf = 0; nf < 4; ++nf) {
            int px = pg*64 + nf*16 + (lane & 15);
            int gp = (ty0 + (px>>5))*WW + tx0 + (px & 31);
            #pragma unroll
            for (int mt = 0; mt < MTW; ++mt) {
                int o_base = (mh*MTW+mt)*16 + colq*4;
                #pragma unroll
                for (int r = 0; r < 4; ++r) {
                    int o = o_base + r;
                    if (o < 18)
                        out[((size_t)n*18 + o)*HWSZ + gp] = acc[mt][nf][r] + b1[o];
                }
            }
        }
    } else {
        float part[4];
        #pragma unroll
        for (int nf = 0; nf < 4; ++nf) {
            float s = 0.f;
            #pragma unroll
            for (int mt = 0; mt < MTW; ++mt) {
                int o_base = (mh*MTW+mt)*16 + colq*4;
                #pragma unroll
                for (int r = 0; r < 4; ++r) {
                    int o = o_base + r;
                    float vv = fmaxf(acc[mt][nf][r] + b1[o], 0.f);
                    s += vv * g2w[o];
                }
            }
            part[nf] = s;
        }
        #pragma unroll
        for (int nf = 0; nf < 4; ++nf) {
            part[nf] += __shfl_xor(part[nf], 16, 64);
            part[nf] += __shfl_xor(part[nf], 32, 64);
        }
        if ((lane & 63) < 16) {
            #pragma unroll
            for (int nf = 0; nf < 4; ++nf)
                gpart[w][nf*16 + lane] = part[nf];
        }
        __syncthreads();
        if (tid < 128) {
            int pxl = tid & 63, pgg = tid >> 6;
            float s = g2b[0];
            #pragma unroll
            for (int m = 0; m < NMH; ++m)
                s += gpart[m*2 + pgg][pxl];
            float g = 1.f / (1.f + expf(-s));
            int px = pgg*64 + pxl;
            int gp = (ty0 + (px>>5))*WW + tx0 + (px & 31);
            out[(size_t)n*HWSZ + gp] = g;
        }
    }
}

// ---------------------------------------------------------------------------
// deformable 3x3 conv via bf16 MFMA, NHWC in/out — frozen at the best-measured
// variant (197 us): tile 2x32, grid (8,144) [XCD-pinned n], block 256 = 4
// waves; quad-coalesced corners, depth-1 prefetch, per-kc validity recompute,
// stride-40 SB, plain __syncthreads.  All structural variants measured worse.
__global__ __launch_bounds__(256) void k_deform_nhwc(
    const u16* __restrict__ nbrh, const float* __restrict__ offs,
    const u16* __restrict__ Wp, const float* __restrict__ ab,
    u16* __restrict__ alig)
{
    constexpr int NKC = 72;
    int n = blockIdx.x, t = blockIdx.y;
    int tx0 = (t % 3) * 32, ty0 = (t / 3) * 2;
    int tid = threadIdx.x, lane = tid & 63, w = tid >> 6;
    int colq = lane >> 4;

    __shared__ __align__(16) u16 pool[8448];      // SBm[2][2560] | TO[32][264]
    __shared__ u32   cpos[576];
    __shared__ float cwy[576], cwx[576];
    u16* SB0 = pool;
    u16* SB1 = pool + 2560;

    const u16* src = nbrh + (size_t)n * PLANE;

    for (int i = tid; i < 576; i += 256) {
        int tt = i >> 6, px = i & 63;
        int y = ty0 + (px>>5), x = tx0 + (px & 31);
        int pp = y*WW + x;
        float oy = offs[((size_t)n*18 + 2*tt    )*HWSZ + pp];
        float ox = offs[((size_t)n*18 + 2*tt + 1)*HWSZ + pp];
        float py  = (float)y + (float)(tt/3 - 1) + oy;
        float pxx = (float)x + (float)(tt%3 - 1) + ox;
        py  = fminf(fmaxf(py,  -4.f), 100.f);
        pxx = fminf(fmaxf(pxx, -4.f), 100.f);
        float y0f = floorf(py), x0f = floorf(pxx);
        cpos[i] = ((u32)((int)y0f + 4) << 16) | (u32)((int)x0f + 4);
        cwy[i] = py - y0f; cwx[i] = pxx - x0f;
    }
    __syncthreads();

    f32x4 acc[4][4];
    #pragma unroll
    for (int mt = 0; mt < 4; ++mt)
        #pragma unroll
        for (int nf = 0; nf < 4; ++nf)
            acc[mt][nf] = (f32x4){0.f,0.f,0.f,0.f};

    int px = tid >> 2, chq = tid & 3;            // produce mapping
    int sbw = px*40 + chq*8;
    int bb[4];
    #pragma unroll
    for (int nf = 0; nf < 4; ++nf)
        bb[nf] = (nf*16 + (lane & 15))*40 + colq*8;

    auto loadC = [&](int kc, int4* q) {
        int tt = kc >> 3, cc = kc & 7;
        int r = (tt<<6) + px;
        u32 cp = cpos[r];
        int y0 = (int)(cp >> 16) - 4, x0 = (int)(cp & 0xffff) - 4;
        bool y0i = (y0 >= 0) & (y0 < HH);
        bool y1i = (y0 >= -1) & (y0 < HH-1);
        bool x0i = (x0 >= 0) & (x0 < WW);
        bool x1i = (x0 >= -1) & (x0 < WW-1);
        int c0 = cc*32 + chq*8;
        int a00 = (y0*WW + x0)*CH + c0;
        int o00 = (y0i & x0i) ? a00            : 0;
        int o01 = (y0i & x1i) ? a00 + CH       : 0;
        int o10 = (y1i & x0i) ? a00 + WW*CH    : 0;
        int o11 = (y1i & x1i) ? a00 + WW*CH+CH : 0;
        int4 z = make_int4(0,0,0,0);
        int4 q0 = *reinterpret_cast<const int4*>(src + o00);
        int4 q1 = *reinterpret_cast<const int4*>(src + o01);
        int4 q2 = *reinterpret_cast<const int4*>(src + o10);
        int4 q3 = *reinterpret_cast<const int4*>(src + o11);
        q[0] = (y0i & x0i) ? q0 : z;
        q[1] = (y0i & x1i) ? q1 : z;
        q[2] = (y1i & x0i) ? q2 : z;
        q[3] = (y1i & x1i) ? q3 : z;
    };
    auto bilerp = [&](int kc, const int4* q) -> int4 {
        int r = ((kc >> 3)<<6) + px;
        float wy = cwy[r], wx = cwx[r];
        float w00 = (1.f-wy)*(1.f-wx), w01 = (1.f-wy)*wx;
        float w10 = wy*(1.f-wx),       w11 = wy*wx;
        int4 res;
        #pragma unroll
        for (int j = 0; j < 4; ++j) {
            u32 u00 = ((const u32*)&q[0])[j], u01 = ((const u32*)&q[1])[j];
            u32 u10 = ((const u32*)&q[2])[j], u11 = ((const u32*)&q[3])[j];
            float lo = w00*bflo(u00) + w01*bflo(u01) + w10*bflo(u10) + w11*bflo(u11);
            float hi = w00*bfhi(u00) + w01*bfhi(u01) + w10*bfhi(u10) + w11*bfhi(u11);
            ((u32*)&res)[j] = pk2bf(lo, hi);
        }
        return res;
    };
    auto loadA = [&](int kc, bf16x8* a) {
        #pragma unroll
        for (int mt = 0; mt < 4; ++mt)
            a[mt] = *reinterpret_cast<const bf16x8*>(
                Wp + (((size_t)(w*4+mt)*NKC + kc)*64 + lane)*8);
    };

    int4 crn[4];
    bf16x8 apf[4];
    loadC(0, crn);
    loadA(0, apf);
    int cur = 0;
    for (int kc = 0; kc < NKC; ++kc) {
        int4 vpk = bilerp(kc, crn);
        u16* SBc = cur ? SB1 : SB0;
        *reinterpret_cast<int4*>(&SBc[sbw]) = vpk;
        bf16x8 a4[4];
        #pragma unroll
        for (int mt = 0; mt < 4; ++mt) a4[mt] = apf[mt];
        if (kc + 1 < NKC) { loadC(kc + 1, crn); loadA(kc + 1, apf); }  // T14
        __syncthreads();
        #pragma unroll
        for (int nf = 0; nf < 4; ++nf) {
            bf16x8 b = *reinterpret_cast<const bf16x8*>(&SBc[bb[nf]]);
            #pragma unroll
            for (int mt = 0; mt < 4; ++mt)
                acc[mt][nf] = __builtin_amdgcn_mfma_f32_16x16x32_bf16(
                                  a4[mt], b, acc[mt][nf], 0, 0, 0);
        }
        cur ^= 1;
    }

    // epilogue: LDS transpose -> coalesced NHWC writes. TO = [32 px][264]
    __syncthreads();
    u16* TO = pool;
    u16* aligp = alig + (size_t)n * PLANE;
    #pragma unroll
    for (int h = 0; h < 2; ++h) {
        #pragma unroll
        for (int sub = 0; sub < 2; ++sub) {
            int nf = 2*h + sub;
            int pl = sub*16 + (lane & 15);
            #pragma unroll
            for (int mt = 0; mt < 4; ++mt) {
                int o = (w*4+mt)*16 + colq*4;
                ushort4 v;
                v.x = f2bf(acc[mt][nf][0] + ab[o]);
                v.y = f2bf(acc[mt][nf][1] + ab[o+1]);
                v.z = f2bf(acc[mt][nf][2] + ab[o+2]);
                v.w = f2bf(acc[mt][nf][3] + ab[o+3]);
                *reinterpret_cast<ushort4*>(&TO[pl*264 + o]) = v;
            }
        }
        __syncthreads();
        #pragma unroll
        for (int it = 0; it < 4; ++it) {
            int i = tid + it*256;
            int pr = i >> 5, ck = i & 31;
            int nf = 2*h + (pr >> 4);
            int pxx = nf*16 + (pr & 15);
            int gp = (ty0 + (pxx>>5))*WW + tx0 + (pxx & 31);
            *reinterpret_cast<int4*>(aligp + (size_t)gp*CH + ck*8) =
                *reinterpret_cast<const int4*>(&TO[pr*264 + ck*8]);
        }
        __syncthreads();
    }
}

// ---------------------------------------------------------------------------
// fuse: softmax over N of g, weighted sum of alig (NHWC bf16), +emb, residual.
__global__ __launch_bounds__(256) void k_fuse_nhwc(
    const float* __restrict__ cur, const u16* __restrict__ alig,
    const float* __restrict__ g, const float* __restrict__ emb,
    float* __restrict__ out)
{
    int p0 = blockIdx.x * 32;
    int tid = threadIdx.x;
    __shared__ float wE[NN][32];
    __shared__ float trans[256][33];

    if (tid < 32) {
        int p = p0 + tid;
        float e[NN], m = -1e30f;
        #pragma unroll
        for (int n = 0; n < NN; ++n) { e[n] = g[n*HWSZ + p]; m = fmaxf(m, e[n]); }
        float se = 0.f;
        #pragma unroll
        for (int n = 0; n < NN; ++n) { e[n] = expf(e[n] - m); se += e[n]; }
        float inv = 1.f / se;
        #pragma unroll
        for (int n = 0; n < NN; ++n) wE[n][tid] = e[n] * inv;
    }
    __syncthreads();

    #pragma unroll
    for (int it = 0; it < 4; ++it) {
        int i = tid + it*256;
        int px = i >> 5, ck = i & 31;
        float a8[8];
        #pragma unroll
        for (int j = 0; j < 8; ++j) a8[j] = 0.f;
        #pragma unroll
        for (int n = 0; n < NN; ++n) {
            int4 v = *reinterpret_cast<const int4*>(
                &alig[((size_t)n*HWSZ + p0 + px)*CH + ck*8]);
            float f = wE[n][px];
            #pragma unroll
            for (int j4 = 0; j4 < 4; ++j4) {
                u32 u = ((const u32*)&v)[j4];
                a8[2*j4]   += bflo(u) * f;
                a8[2*j4+1] += bfhi(u) * f;
            }
        }
        #pragma unroll
        for (int j = 0; j < 8; ++j) {
            int c = ck*8 + j;
            trans[c][px ^ (c & 31)] = a8[j] + emb[c];
        }
    }
    __syncthreads();
    for (int it = 0; it < 32; ++it) {
        int c = (tid >> 5) + it*8, px = tid & 31;
        int idx = c*HWSZ + p0 + px;
        out[idx] = cur[idx] + 0.5f * trans[c][px ^ (c & 31)];
    }
}

// ---------------------------------------------------------------------------
extern "C" void kernel_launch(void* const* d_in, const int* in_sizes, int n_in,
                              void* d_out, int out_size, void* d_ws, size_t ws_size,
                              hipStream_t stream)
{
    const float* cur = (const float*)d_in[0];
    const float* nbr = (const float*)d_in[1];
    const float* cd  = (const float*)d_in[2];
    const float* aw  = (const float*)d_in[3];
    const float* ab  = (const float*)d_in[4];
    const float* ow  = (const float*)d_in[5];
    const float* ob  = (const float*)d_in[6];
    const float* g1w = (const float*)d_in[7];
    const float* g1b = (const float*)d_in[8];
    const float* g2w = (const float*)d_in[9];
    const float* g2b = (const float*)d_in[10];
    const float* ew  = (const float*)d_in[11];
    const float* eb  = (const float*)d_in[12];
    float* out = (float*)d_out;
    float* ws  = (float*)d_ws;

    float* offs = ws;                          // 1,327,104 f
    float* gbuf = offs + 1327104;              // 73,728 f
    float* emb  = gbuf + 73728;                // 256 f
    u16* nbrh = (u16*)(emb + 256);             // 8 * PLANE
    u16* curh = nbrh + (size_t)NN*PLANE;       // PLANE (contiguous after nbrh)
    u16* alig = curh + PLANE;                  // 8 * PLANE (NHWC)
    u16* wpO  = alig + (size_t)NN*PLANE;       // 32*4608
    u16* wpG  = wpO + 147456;                  // 128*4608
    u16* wpA  = wpG + 589824;                  // 256*2304

    k_emb_sum<<<dim3(1), dim3(256), 0, stream>>>(cd, ew, eb, emb);
    k_to_nhwc<<<dim3(144, 9), dim3(256), 0, stream>>>(nbr, cur, nbrh);
    k_pack_w<<<dim3((32*4608 + 255)/256), dim3(256), 0, stream>>>(ow, wpO, 18, 32, 512);
    k_pack_w<<<dim3((128*4608 + 255)/256), dim3(256), 0, stream>>>(g1w, wpG, 128, 128, 512);
    k_pack_w<<<dim3((256*2304 + 255)/256), dim3(256), 0, stream>>>(aw, wpA, 256, 256, 256);

    // offset conv: concat(nbr_n, cur) -> 18 ch (padded to 32), XCD-pinned n
    k_conv_nhwc<1, 2, 0><<<dim3(8, 72), dim3(256), 0, stream>>>(
        nbrh, (long)PLANE, curh, 0L, wpO, ob, nullptr, nullptr, offs);
    // deformable conv -> alig (NHWC bf16), XCD-pinned n
    k_deform_nhwc<<<dim3(8, 144), dim3(256), 0, stream>>>(nbrh, offs, wpA, ab, alig);
    // gate: concat(cur, alig_n) -> 128 -> relu -> 1x1 -> sigmoid, XCD-pinned n
    k_conv_nhwc<2, 4, 1><<<dim3(8, 72), dim3(512), 0, stream>>>(
        curh, 0L, alig, (long)PLANE, wpG, g1b, g2w, g2b, gbuf);
    // softmax + fuse + residual
    k_fuse_nhwc<<<dim3(288), dim3(256), 0, stream>>>(cur, alig, gbuf, emb, out);
}

// Round 15
// 366.938 us; speedup vs baseline: 2.4571x; 1.0356x over previous
//
#include <hip/hip_runtime.h>
#include <math.h>

// Problem constants: B=1, C=256, H=96, W=96, N=8
#define CH   256
#define HH   96
#define WW   96
#define NN   8
#define HWSZ 9216
#define PLANE (HWSZ*CH)          // elements per neighbor in NHWC

typedef unsigned short u16;
typedef unsigned int   u32;
typedef short bf16x8 __attribute__((ext_vector_type(8)));
typedef float f32x4  __attribute__((ext_vector_type(4)));
typedef float f32x2  __attribute__((ext_vector_type(2)));

__device__ inline u16 f2bf(float f) {
    union { float f; u32 u; } v; v.f = f;
    u32 r = v.u + 0x7FFF + ((v.u >> 16) & 1);   // RNE
    return (u16)(r >> 16);
}
__device__ inline float bflo(u32 u) {
    union { u32 u; float f; } v; v.u = u << 16; return v.f;
}
__device__ inline float bfhi(u32 u) {
    union { u32 u; float f; } v; v.u = u & 0xffff0000u; return v.f;
}
__device__ inline u32 pk2bf(float lo, float hi) {   // RNE pack pair
    union { float f; u32 u; } a, b; a.f = lo; b.f = hi;
    u32 ra = a.u + 0x7FFF + ((a.u >> 16) & 1);
    u32 rb = b.u + 0x7FFF + ((b.u >> 16) & 1);
    return (ra >> 16) | (rb & 0xffff0000u);
}

// ---------------------------------------------------------------------------
// pack one weight element: w[O][CIN][3][3] (fp32 OIHW) -> bf16 A-fragment.
// K = tap*CIN + c (tap-major); kc = K>>5.
__device__ inline void pack_one(const float* __restrict__ w, u16* __restrict__ wp,
                                int O, int O_pad, int CIN, int idx)
{
    int total = O_pad * CIN * 9;
    if (idx >= total) return;
    int o = idx / (CIN * 9);
    int K = idx % (CIN * 9);
    int tap = K / CIN, c = K % CIN;
    float v = (o < O) ? w[((size_t)o * CIN + c) * 9 + tap] : 0.f;
    int NKC = (CIN * 9) >> 5;
    int kc = K >> 5, kl = K & 31;
    int lane = (kl >> 3) * 16 + (o & 15);
    size_t dstp = (((size_t)(o >> 4) * NKC + kc) * 64 + lane) * 8 + (kl & 7);
    wp[dstp] = f2bf(v);
}

// ---------------------------------------------------------------------------
// merged prep: [0,1296) NCHW->NHWC transpose (n<8 nbr, n==8 cur);
// [1296,1872) pack offset-w; [1872,4176) pack gate1-w; [4176,6480) pack
// align-w; [6480] coord-embedding sum.  One launch, branches block-uniform.
__global__ __launch_bounds__(256) void k_prep(
    const float* __restrict__ nbr, const float* __restrict__ cur,
    u16* __restrict__ nhwc,
    const float* __restrict__ ow,  u16* __restrict__ wpO,
    const float* __restrict__ g1w, u16* __restrict__ wpG,
    const float* __restrict__ aw,  u16* __restrict__ wpA,
    const float* __restrict__ cd,  const float* __restrict__ ew,
    const float* __restrict__ eb,  float* __restrict__ emb)
{
    int bid = blockIdx.x, tid = threadIdx.x;
    __shared__ u16 T[64][262];

    if (bid < 1296) {
        int n = bid / 144;
        const float* src = (n < 8) ? nbr + (size_t)n * CH * HWSZ : cur;
        int p0 = (bid % 144) * 64;
        int px4 = (tid & 15) * 4, cb = tid >> 4;
        for (int it = 0; it < 16; ++it) {
            int c = cb + it*16;
            float4 v = *reinterpret_cast<const float4*>(
                src + (size_t)c*HWSZ + p0 + px4);
            T[px4+0][c] = f2bf(v.x);
            T[px4+1][c] = f2bf(v.y);
            T[px4+2][c] = f2bf(v.z);
            T[px4+3][c] = f2bf(v.w);
        }
        __syncthreads();
        int pxb = tid >> 5, ck = tid & 31;
        for (int it = 0; it < 8; ++it) {
            int p = pxb + it*8;
            *reinterpret_cast<int4*>(
                nhwc + (size_t)n*PLANE + (size_t)(p0+p)*CH + ck*8) =
                *reinterpret_cast<const int4*>(&T[p][ck*8]);
        }
    } else if (bid < 1872) {
        pack_one(ow, wpO, 18, 32, 512, (bid - 1296)*256 + tid);
    } else if (bid < 4176) {
        pack_one(g1w, wpG, 128, 128, 512, (bid - 1872)*256 + tid);
    } else if (bid < 6480) {
        pack_one(aw, wpA, 256, 256, 256, (bid - 4176)*256 + tid);
    } else {
        int c = tid;
        float s = 0.f;
        for (int n = 0; n < NN; ++n) {
            float d = eb[c];
            #pragma unroll
            for (int j = 0; j < 4; ++j) d += cd[n*4 + j] * ew[c*4 + j];
            s += d;
        }
        emb[c] = s;
    }
}

// ---------------------------------------------------------------------------
// shift-conv 3x3 pad1 on concat(in0_n, in1_n) (512 in-ch, NHWC bf16) via MFMA.
// tile 4 rows x 32 cols (128 px), grid (8, 72) [XCD-pinned n].
// NMH*2 waves: mh = w>>1 (M-group), pg = w&1 (64-px group).
// T14 async-STAGE: next chunk's global loads issued right after the SB-ready
// barrier so they fly under the 9-tap MFMA phase.
template<int MTW, int NMH, int EPI>
__global__ __launch_bounds__(NMH*128) void k_conv_nhwc(
    const u16* __restrict__ in0, long s0,
    const u16* __restrict__ in1, long s1,
    const u16* __restrict__ Wp, const float* __restrict__ b1,
    const float* __restrict__ g2w, const float* __restrict__ g2b,
    float* __restrict__ out)
{
    constexpr int NKC = 144, NCC = 16;
    constexpr int BS  = NMH * 128;
    constexpr int KK  = (816 + BS - 1) / BS;
    int n = blockIdx.x, t = blockIdx.y;
    int tx0 = (t % 3) * 32, ty0 = (t / 3) * 4;
    int tid = threadIdx.x, lane = tid & 63, w = tid >> 6;
    int mh = w >> 1, pg = w & 1;
    int colq = lane >> 4;

    __shared__ __align__(16) u16 SB[204*40];
    __shared__ float gpart[8][64];

    f32x4 acc[MTW][4];
    #pragma unroll
    for (int mt = 0; mt < MTW; ++mt)
        #pragma unroll
        for (int nf = 0; nf < 4; ++nf)
            acc[mt][nf] = (f32x4){0.f,0.f,0.f,0.f};

    int bidx[4];
    #pragma unroll
    for (int nf = 0; nf < 4; ++nf) {
        int px = pg*64 + nf*16 + (lane & 15);
        int row = px >> 5, col = px & 31;
        bidx[nf] = ((row+1)*34 + (col+1))*40 + colq*8;
    }

    int4 stg[KK];
    auto ldreg = [&](int cc) {
        const u16* base = (cc < 8) ? in0 + (size_t)n*s0 + cc*32
                                   : in1 + (size_t)n*s1 + (cc-8)*32;
        #pragma unroll
        for (int k = 0; k < KK; ++k) {
            int i = tid + k*BS;
            int4 v = make_int4(0,0,0,0);
            if (i < 816) {
                int ph = i >> 2, q = i & 3;
                int r = ph / 34, col = ph - r*34;
                int y = ty0 - 1 + r, x = tx0 - 1 + col;
                if (((unsigned)y < (unsigned)HH) && ((unsigned)x < (unsigned)WW))
                    v = *reinterpret_cast<const int4*>(base + (y*WW + x)*CH + q*8);
            }
            stg[k] = v;
        }
    };
    auto streg = [&]() {
        #pragma unroll
        for (int k = 0; k < KK; ++k) {
            int i = tid + k*BS;
            if (i < 816) {
                int ph = i >> 2, q = i & 3;
                *reinterpret_cast<int4*>(&SB[ph*40 + q*8]) = stg[k];
            }
        }
    };

    ldreg(0);
    for (int cc = 0; cc < NCC; ++cc) {
        __syncthreads();
        streg();
        __syncthreads();
        if (cc + 1 < NCC) ldreg(cc + 1);      // T14
        #pragma unroll
        for (int tap = 0; tap < 9; ++tap) {
            int kc = tap*NCC + cc;
            bf16x8 a[MTW];
            #pragma unroll
            for (int mt = 0; mt < MTW; ++mt)
                a[mt] = *reinterpret_cast<const bf16x8*>(
                    Wp + (((size_t)(mh*MTW+mt)*NKC + kc)*64 + lane)*8);
            const int dy = tap/3 - 1, dx = tap%3 - 1;
            #pragma unroll
            for (int nf = 0; nf < 4; ++nf) {
                bf16x8 b = *reinterpret_cast<const bf16x8*>(
                    &SB[bidx[nf] + (dy*34 + dx)*40]);
                #pragma unroll
                for (int mt = 0; mt < MTW; ++mt)
                    acc[mt][nf] = __builtin_amdgcn_mfma_f32_16x16x32_bf16(
                                      a[mt], b, acc[mt][nf], 0, 0, 0);
            }
        }
    }

    if (EPI == 0) {
        #pragma unroll
        for (int nf = 0; nf < 4; ++nf) {
            int px = pg*64 + nf*16 + (lane & 15);
            int gp = (ty0 + (px>>5))*WW + tx0 + (px & 31);
            #pragma unroll
            for (int mt = 0; mt < MTW; ++mt) {
                int o_base = (mh*MTW+mt)*16 + colq*4;
                #pragma unroll
                for (int r = 0; r < 4; ++r) {
                    int o = o_base + r;
                    if (o < 18)
                        out[((size_t)n*18 + o)*HWSZ + gp] = acc[mt][nf][r] + b1[o];
                }
            }
        }
    } else {
        float part[4];
        #pragma unroll
        for (int nf = 0; nf < 4; ++nf) {
            float s = 0.f;
            #pragma unroll
            for (int mt = 0; mt < MTW; ++mt) {
                int o_base = (mh*MTW+mt)*16 + colq*4;
                #pragma unroll
                for (int r = 0; r < 4; ++r) {
                    int o = o_base + r;
                    float vv = fmaxf(acc[mt][nf][r] + b1[o], 0.f);
                    s += vv * g2w[o];
                }
            }
            part[nf] = s;
        }
        #pragma unroll
        for (int nf = 0; nf < 4; ++nf) {
            part[nf] += __shfl_xor(part[nf], 16, 64);
            part[nf] += __shfl_xor(part[nf], 32, 64);
        }
        if ((lane & 63) < 16) {
            #pragma unroll
            for (int nf = 0; nf < 4; ++nf)
                gpart[w][nf*16 + lane] = part[nf];
        }
        __syncthreads();
        if (tid < 128) {
            int pxl = tid & 63, pgg = tid >> 6;
            float s = g2b[0];
            #pragma unroll
            for (int m = 0; m < NMH; ++m)
                s += gpart[m*2 + pgg][pxl];
            float g = 1.f / (1.f + expf(-s));
            int px = pgg*64 + pxl;
            int gp = (ty0 + (px>>5))*WW + tx0 + (px & 31);
            out[(size_t)n*HWSZ + gp] = g;
        }
    }
}

// ---------------------------------------------------------------------------
// deformable 3x3 conv via bf16 MFMA, NHWC in/out — frozen at the best-measured
// variant (197 us): tile 2x32, grid (8,144) [XCD-pinned n], block 256 = 4
// waves; quad-coalesced corners, depth-1 prefetch, per-kc validity recompute,
// stride-40 SB, plain __syncthreads.  All structural variants measured worse.
__global__ __launch_bounds__(256) void k_deform_nhwc(
    const u16* __restrict__ nbrh, const float* __restrict__ offs,
    const u16* __restrict__ Wp, const float* __restrict__ ab,
    u16* __restrict__ alig)
{
    constexpr int NKC = 72;
    int n = blockIdx.x, t = blockIdx.y;
    int tx0 = (t % 3) * 32, ty0 = (t / 3) * 2;
    int tid = threadIdx.x, lane = tid & 63, w = tid >> 6;
    int colq = lane >> 4;

    __shared__ __align__(16) u16 pool[8448];      // SBm[2][2560] | TO[32][264]
    __shared__ u32   cpos[576];
    __shared__ float cwy[576], cwx[576];
    u16* SB0 = pool;
    u16* SB1 = pool + 2560;

    const u16* src = nbrh + (size_t)n * PLANE;

    for (int i = tid; i < 576; i += 256) {
        int tt = i >> 6, px = i & 63;
        int y = ty0 + (px>>5), x = tx0 + (px & 31);
        int pp = y*WW + x;
        float oy = offs[((size_t)n*18 + 2*tt    )*HWSZ + pp];
        float ox = offs[((size_t)n*18 + 2*tt + 1)*HWSZ + pp];
        float py  = (float)y + (float)(tt/3 - 1) + oy;
        float pxx = (float)x + (float)(tt%3 - 1) + ox;
        py  = fminf(fmaxf(py,  -4.f), 100.f);
        pxx = fminf(fmaxf(pxx, -4.f), 100.f);
        float y0f = floorf(py), x0f = floorf(pxx);
        cpos[i] = ((u32)((int)y0f + 4) << 16) | (u32)((int)x0f + 4);
        cwy[i] = py - y0f; cwx[i] = pxx - x0f;
    }
    __syncthreads();

    f32x4 acc[4][4];
    #pragma unroll
    for (int mt = 0; mt < 4; ++mt)
        #pragma unroll
        for (int nf = 0; nf < 4; ++nf)
            acc[mt][nf] = (f32x4){0.f,0.f,0.f,0.f};

    int px = tid >> 2, chq = tid & 3;            // produce mapping
    int sbw = px*40 + chq*8;
    int bb[4];
    #pragma unroll
    for (int nf = 0; nf < 4; ++nf)
        bb[nf] = (nf*16 + (lane & 15))*40 + colq*8;

    auto loadC = [&](int kc, int4* q) {
        int tt = kc >> 3, cc = kc & 7;
        int r = (tt<<6) + px;
        u32 cp = cpos[r];
        int y0 = (int)(cp >> 16) - 4, x0 = (int)(cp & 0xffff) - 4;
        bool y0i = (y0 >= 0) & (y0 < HH);
        bool y1i = (y0 >= -1) & (y0 < HH-1);
        bool x0i = (x0 >= 0) & (x0 < WW);
        bool x1i = (x0 >= -1) & (x0 < WW-1);
        int c0 = cc*32 + chq*8;
        int a00 = (y0*WW + x0)*CH + c0;
        int o00 = (y0i & x0i) ? a00            : 0;
        int o01 = (y0i & x1i) ? a00 + CH       : 0;
        int o10 = (y1i & x0i) ? a00 + WW*CH    : 0;
        int o11 = (y1i & x1i) ? a00 + WW*CH+CH : 0;
        int4 z = make_int4(0,0,0,0);
        int4 q0 = *reinterpret_cast<const int4*>(src + o00);
        int4 q1 = *reinterpret_cast<const int4*>(src + o01);
        int4 q2 = *reinterpret_cast<const int4*>(src + o10);
        int4 q3 = *reinterpret_cast<const int4*>(src + o11);
        q[0] = (y0i & x0i) ? q0 : z;
        q[1] = (y0i & x1i) ? q1 : z;
        q[2] = (y1i & x0i) ? q2 : z;
        q[3] = (y1i & x1i) ? q3 : z;
    };
    auto bilerp = [&](int kc, const int4* q) -> int4 {
        int r = ((kc >> 3)<<6) + px;
        float wy = cwy[r], wx = cwx[r];
        float w00 = (1.f-wy)*(1.f-wx), w01 = (1.f-wy)*wx;
        float w10 = wy*(1.f-wx),       w11 = wy*wx;
        int4 res;
        #pragma unroll
        for (int j = 0; j < 4; ++j) {
            u32 u00 = ((const u32*)&q[0])[j], u01 = ((const u32*)&q[1])[j];
            u32 u10 = ((const u32*)&q[2])[j], u11 = ((const u32*)&q[3])[j];
            float lo = w00*bflo(u00) + w01*bflo(u01) + w10*bflo(u10) + w11*bflo(u11);
            float hi = w00*bfhi(u00) + w01*bfhi(u01) + w10*bfhi(u10) + w11*bfhi(u11);
            ((u32*)&res)[j] = pk2bf(lo, hi);
        }
        return res;
    };
    auto loadA = [&](int kc, bf16x8* a) {
        #pragma unroll
        for (int mt = 0; mt < 4; ++mt)
            a[mt] = *reinterpret_cast<const bf16x8*>(
                Wp + (((size_t)(w*4+mt)*NKC + kc)*64 + lane)*8);
    };

    int4 crn[4];
    bf16x8 apf[4];
    loadC(0, crn);
    loadA(0, apf);
    int cur = 0;
    for (int kc = 0; kc < NKC; ++kc) {
        int4 vpk = bilerp(kc, crn);
        u16* SBc = cur ? SB1 : SB0;
        *reinterpret_cast<int4*>(&SBc[sbw]) = vpk;
        bf16x8 a4[4];
        #pragma unroll
        for (int mt = 0; mt < 4; ++mt) a4[mt] = apf[mt];
        if (kc + 1 < NKC) { loadC(kc + 1, crn); loadA(kc + 1, apf); }  // T14
        __syncthreads();
        #pragma unroll
        for (int nf = 0; nf < 4; ++nf) {
            bf16x8 b = *reinterpret_cast<const bf16x8*>(&SBc[bb[nf]]);
            #pragma unroll
            for (int mt = 0; mt < 4; ++mt)
                acc[mt][nf] = __builtin_amdgcn_mfma_f32_16x16x32_bf16(
                                  a4[mt], b, acc[mt][nf], 0, 0, 0);
        }
        cur ^= 1;
    }

    // epilogue: LDS transpose -> coalesced NHWC writes. TO = [32 px][264]
    __syncthreads();
    u16* TO = pool;
    u16* aligp = alig + (size_t)n * PLANE;
    #pragma unroll
    for (int h = 0; h < 2; ++h) {
        #pragma unroll
        for (int sub = 0; sub < 2; ++sub) {
            int nf = 2*h + sub;
            int pl = sub*16 + (lane & 15);
            #pragma unroll
            for (int mt = 0; mt < 4; ++mt) {
                int o = (w*4+mt)*16 + colq*4;
                ushort4 v;
                v.x = f2bf(acc[mt][nf][0] + ab[o]);
                v.y = f2bf(acc[mt][nf][1] + ab[o+1]);
                v.z = f2bf(acc[mt][nf][2] + ab[o+2]);
                v.w = f2bf(acc[mt][nf][3] + ab[o+3]);
                *reinterpret_cast<ushort4*>(&TO[pl*264 + o]) = v;
            }
        }
        __syncthreads();
        #pragma unroll
        for (int it = 0; it < 4; ++it) {
            int i = tid + it*256;
            int pr = i >> 5, ck = i & 31;
            int nf = 2*h + (pr >> 4);
            int pxx = nf*16 + (pr & 15);
            int gp = (ty0 + (pxx>>5))*WW + tx0 + (pxx & 31);
            *reinterpret_cast<int4*>(aligp + (size_t)gp*CH + ck*8) =
                *reinterpret_cast<const int4*>(&TO[pr*264 + ck*8]);
        }
        __syncthreads();
    }
}

// ---------------------------------------------------------------------------
// fuse: softmax over N of g, weighted sum of alig (NHWC bf16), +emb, residual.
// grid (288, 2): x = 32-px group, y = 128-channel half (doubles block count
// vs r14's 288 total -> ~2.25 blocks/CU, hides load latency in the tail).
__global__ __launch_bounds__(256) void k_fuse_nhwc(
    const float* __restrict__ cur, const u16* __restrict__ alig,
    const float* __restrict__ g, const float* __restrict__ emb,
    float* __restrict__ out)
{
    int p0 = blockIdx.x * 32;
    int ch0 = blockIdx.y * 128;
    int tid = threadIdx.x;
    __shared__ float wE[NN][32];
    __shared__ float trans[128][33];

    if (tid < 32) {
        int p = p0 + tid;
        float e[NN], m = -1e30f;
        #pragma unroll
        for (int n = 0; n < NN; ++n) { e[n] = g[n*HWSZ + p]; m = fmaxf(m, e[n]); }
        float se = 0.f;
        #pragma unroll
        for (int n = 0; n < NN; ++n) { e[n] = expf(e[n] - m); se += e[n]; }
        float inv = 1.f / se;
        #pragma unroll
        for (int n = 0; n < NN; ++n) wE[n][tid] = e[n] * inv;
    }
    __syncthreads();

    #pragma unroll
    for (int it = 0; it < 2; ++it) {
        int i = tid + it*256;
        int px = i >> 4, ck = i & 15;           // 32 px x 16 ch-octets (128 ch)
        float a8[8];
        #pragma unroll
        for (int j = 0; j < 8; ++j) a8[j] = 0.f;
        #pragma unroll
        for (int n = 0; n < NN; ++n) {
            int4 v = *reinterpret_cast<const int4*>(
                &alig[((size_t)n*HWSZ + p0 + px)*CH + ch0 + ck*8]);
            float f = wE[n][px];
            #pragma unroll
            for (int j4 = 0; j4 < 4; ++j4) {
                u32 u = ((const u32*)&v)[j4];
                a8[2*j4]   += bflo(u) * f;
                a8[2*j4+1] += bfhi(u) * f;
            }
        }
        #pragma unroll
        for (int j = 0; j < 8; ++j) {
            int c = ck*8 + j;
            trans[c][px ^ (c & 31)] = a8[j] + emb[ch0 + c];
        }
    }
    __syncthreads();
    for (int it = 0; it < 16; ++it) {
        int c = (tid >> 5) + it*8, px = tid & 31;
        int idx = (ch0 + c)*HWSZ + p0 + px;
        out[idx] = cur[idx] + 0.5f * trans[c][px ^ (c & 31)];
    }
}

// ---------------------------------------------------------------------------
extern "C" void kernel_launch(void* const* d_in, const int* in_sizes, int n_in,
                              void* d_out, int out_size, void* d_ws, size_t ws_size,
                              hipStream_t stream)
{
    const float* cur = (const float*)d_in[0];
    const float* nbr = (const float*)d_in[1];
    const float* cd  = (const float*)d_in[2];
    const float* aw  = (const float*)d_in[3];
    const float* ab  = (const float*)d_in[4];
    const float* ow  = (const float*)d_in[5];
    const float* ob  = (const float*)d_in[6];
    const float* g1w = (const float*)d_in[7];
    const float* g1b = (const float*)d_in[8];
    const float* g2w = (const float*)d_in[9];
    const float* g2b = (const float*)d_in[10];
    const float* ew  = (const float*)d_in[11];
    const float* eb  = (const float*)d_in[12];
    float* out = (float*)d_out;
    float* ws  = (float*)d_ws;

    float* offs = ws;                          // 1,327,104 f
    float* gbuf = offs + 1327104;              // 73,728 f
    float* emb  = gbuf + 73728;                // 256 f
    u16* nbrh = (u16*)(emb + 256);             // 8 * PLANE
    u16* curh = nbrh + (size_t)NN*PLANE;       // PLANE (contiguous after nbrh)
    u16* alig = curh + PLANE;                  // 8 * PLANE (NHWC)
    u16* wpO  = alig + (size_t)NN*PLANE;       // 32*4608
    u16* wpG  = wpO + 147456;                  // 128*4608
    u16* wpA  = wpG + 589824;                  // 256*2304

    // merged prep: transpose + 3x weight pack + coord embedding (one launch)
    k_prep<<<dim3(6481), dim3(256), 0, stream>>>(
        nbr, cur, nbrh, ow, wpO, g1w, wpG, aw, wpA, cd, ew, eb, emb);

    // offset conv: concat(nbr_n, cur) -> 18 ch (padded to 32), XCD-pinned n
    k_conv_nhwc<1, 2, 0><<<dim3(8, 72), dim3(256), 0, stream>>>(
        nbrh, (long)PLANE, curh, 0L, wpO, ob, nullptr, nullptr, offs);
    // deformable conv -> alig (NHWC bf16), XCD-pinned n
    k_deform_nhwc<<<dim3(8, 144), dim3(256), 0, stream>>>(nbrh, offs, wpA, ab, alig);
    // gate: concat(cur, alig_n) -> 128 -> relu -> 1x1 -> sigmoid, XCD-pinned n
    k_conv_nhwc<2, 4, 1><<<dim3(8, 72), dim3(512), 0, stream>>>(
        curh, 0L, alig, (long)PLANE, wpG, g1b, g2w, g2b, gbuf);
    // softmax + fuse + residual
    k_fuse_nhwc<<<dim3(288, 2), dim3(256), 0, stream>>>(cur, alig, gbuf, emb, out);
}